// Round 4
// baseline (193.061 us; speedup 1.0000x reference)
//
#include <hip/hip_runtime.h>
#include <cstdint>
#include <cstddef>

// Problem constants
#define NIMG 32
#define C    128
#define OC   128
#define HW   112
#define HWSZ (HW * HW)      // 12544
#define PHW  114            // padded spatial dim
#define PIMG (PHW * PHW)    // 12996 padded cells per image
#define NTAP 9

// ---------------------------------------------------------------------------
// Zero-fill the padded packed-x buffer (borders must read as 0 bits).
__global__ void fill_zero_u4(uint4* __restrict__ p, int n) {
    int i = blockIdx.x * blockDim.x + threadIdx.x;
    if (i < n) p[i] = make_uint4(0u, 0u, 0u, 0u);
}

// ---------------------------------------------------------------------------
// Pack weights: (O=128, I=128, 3, 3) fp32 -> per (o,tap) 128-bit mask (uint4),
// bit c set iff w[o][c][tap] < 0.  Also store popcount per (o,tap).
__global__ void pack_weights(const float* __restrict__ w,
                             uint4* __restrict__ wpk,
                             int* __restrict__ popcw) {
    int idx = blockIdx.x * blockDim.x + threadIdx.x;   // (o, tap)
    if (idx >= OC * NTAP) return;
    int o = idx / NTAP, tap = idx % NTAP;
    uint32_t m[4] = {0u, 0u, 0u, 0u};
    for (int c = 0; c < C; ++c) {
        uint32_t bit = __float_as_uint(w[(size_t)(o * C + c) * NTAP + tap]) >> 31;
        m[c >> 5] |= bit << (c & 31);
    }
    wpk[idx] = make_uint4(m[0], m[1], m[2], m[3]);
    popcw[idx] = __popc(m[0]) + __popc(m[1]) + __popc(m[2]) + __popc(m[3]);
}

// ---------------------------------------------------------------------------
// Border-base table: base[pat][o] = 9*C - sum over invalid taps of
// (C - 2*popcw[o][tap]), so that out = base - 2*popc_total directly.
__global__ void mk_base(const int* __restrict__ popcw, int* __restrict__ baset) {
    int idx = blockIdx.x * blockDim.x + threadIdx.x;   // pat*128 + o
    if (idx >= 9 * OC) return;
    int pat = idx >> 7, o = idx & 127;
    int pt = pat / 3, pw = pat % 3;
    int inv = 0;
    if (pt == 1) inv |= 0b000000111;
    if (pt == 2) inv |= 0b111000000;
    if (pw == 1) inv |= 0b001001001;
    if (pw == 2) inv |= 0b100100100;
    int s = NTAP * C;
    for (int t = 0; t < NTAP; ++t)
        if ((inv >> t) & 1) s -= C - 2 * popcw[o * NTAP + t];
    baset[idx] = s;
}

// ---------------------------------------------------------------------------
// Pack activations: x (N,C,112,112) fp32 -> padded bit buffer.
// One thread = (n, word-of-32-channels, 4 consecutive w positions).
// float4 loads: 16 B/lane coalescing sweet spot; 1568 blocks.
__global__ void pack_x(const float* __restrict__ x, uint32_t* __restrict__ pxw) {
    int t = blockIdx.x * blockDim.x + threadIdx.x;
    const int per_img = HWSZ / 4;                      // 3136 (divisible by 64)
    if (t >= NIMG * 4 * per_img) return;
    int p = t % per_img;                               // lane-fastest -> coalesced
    int g = t / per_img;
    int word = g & 3, n = g >> 2;
    int hw0 = p * 4;
    int h = hw0 / HW, w0 = hw0 % HW;                   // 112 % 4 == 0: no row crossing

    uint32_t m[4] = {0u, 0u, 0u, 0u};
    const float* xp = x + ((size_t)n * C + word * 32) * HWSZ + hw0;
    #pragma unroll
    for (int cc = 0; cc < 32; ++cc) {
        float4 v = *reinterpret_cast<const float4*>(xp + (size_t)cc * HWSZ);
        m[0] |= (__float_as_uint(v.x) >> 31) << cc;
        m[1] |= (__float_as_uint(v.y) >> 31) << cc;
        m[2] |= (__float_as_uint(v.z) >> 31) << cc;
        m[3] |= (__float_as_uint(v.w) >> 31) << cc;
    }
    uint32_t* dst = pxw + (((size_t)n * PIMG + (size_t)(h + 1) * PHW + (w0 + 1)) << 2) + word;
    dst[0]  = m[0];
    dst[4]  = m[1];
    dst[8]  = m[2];
    dst[12] = m[3];
}

// ---------------------------------------------------------------------------
__device__ __forceinline__ void bcnt_acc(uint32_t& acc, uint32_t v) {
    // acc = popc(v) + acc, guaranteed single instruction; "+v" pins acc to a VGPR
    asm("v_bcnt_u32_b32 %0, %1, %0" : "+v"(acc) : "v"(v));
}

// Binary conv: out[n][o][h][w] = base[pat][o] - 2*popc(X^W).
// Loop-inverted: taps OUTER, o INNER, acc[32] accumulators. Live state is
// acc[32]+xv[4]+temps (~60 VGPR) instead of xt[36]+weights; launch_bounds
// (256,4) raises the VGPR cap to 128 so nothing round-trips through AGPRs.
// v_bcnt chains straight into acc[o] (no separate adds). Weights are staged
// in LDS transposed [tap][o] -> wave-uniform broadcast ds_read_b128 with
// immediate offsets on the lgkm pipe, overlapping the VALU stream.
__global__ __launch_bounds__(256, 4) void bconv(const uint4* __restrict__ px,
                                                const uint4* __restrict__ wpk,
                                                const int* __restrict__ baset,
                                                float* __restrict__ out) {
    __shared__ uint4 swt[NTAP][32];    // [tap][o], 4.6 KB
    __shared__ int sbase[9 * 32];      // base[pat][o-slab], 1.15 KB

    int o0 = blockIdx.y * 32;
    for (int i = threadIdx.x; i < NTAP * 32; i += 256) {
        int t = i >> 5, o = i & 31;
        swt[t][o] = wpk[(size_t)(o0 + o) * NTAP + t];
    }
    for (int i = threadIdx.x; i < 9 * 32; i += 256) {
        int pat = i >> 5, ii = i & 31;
        sbase[i] = baset[pat * OC + o0 + ii];
    }
    __syncthreads();

    int tile = blockIdx.x;                 // 0 .. 32*49-1
    int n = tile / 49;
    int hw = (tile % 49) * 256 + threadIdx.x;
    int h = hw / HW, w = hw % HW;

    const uint4* xbase = px + (size_t)n * PIMG + (size_t)h * PHW + w;

    uint32_t acc[32];
    #pragma unroll
    for (int o = 0; o < 32; ++o) acc[o] = 0u;

    #pragma unroll
    for (int t = 0; t < NTAP; ++t) {
        const int kh = t / 3, kw = t % 3;
        uint4 xv = xbase[kh * PHW + kw];   // global, L1/L2-hot
        #pragma unroll
        for (int o = 0; o < 32; ++o) {
            uint4 wv = swt[t][o];          // uniform ds_read_b128, imm offset
            bcnt_acc(acc[o], xv.x ^ wv.x);
            bcnt_acc(acc[o], xv.y ^ wv.y);
            bcnt_acc(acc[o], xv.z ^ wv.z);
            bcnt_acc(acc[o], xv.w ^ wv.w);
        }
    }

    int pt = (h == 0) ? 1 : ((h == HW - 1) ? 2 : 0);
    int pw = (w == 0) ? 1 : ((w == HW - 1) ? 2 : 0);
    const int* cb = sbase + (pt * 3 + pw) * 32;        // LDS, per-lane

    float* outbase = out + (size_t)(n * OC + o0) * HWSZ + hw;
    #pragma unroll
    for (int o = 0; o < 32; ++o) {
        int val = cb[o] - 2 * (int)acc[o];
        outbase[(size_t)o * HWSZ] = (float)val;        // uniform base + voffset
    }
}

// ---------------------------------------------------------------------------
extern "C" void kernel_launch(void* const* d_in, const int* in_sizes, int n_in,
                              void* d_out, int out_size, void* d_ws, size_t ws_size,
                              hipStream_t stream) {
    const float* x   = (const float*)d_in[0];
    const float* wts = (const float*)d_in[1];
    float* out = (float*)d_out;

    uint8_t* ws = (uint8_t*)d_ws;
    size_t px_bytes   = (size_t)NIMG * PIMG * sizeof(uint4);   // 6,653,952
    size_t wpk_bytes  = (size_t)OC * NTAP * sizeof(uint4);     // 18,432
    size_t popw_bytes = (size_t)OC * NTAP * sizeof(int);       // 4,608
    uint4* px    = (uint4*)ws;
    uint4* wpk   = (uint4*)(ws + px_bytes);
    int*   popcw = (int*)(ws + px_bytes + wpk_bytes);
    int*   baset = (int*)(ws + px_bytes + wpk_bytes + popw_bytes);

    int nfill = NIMG * PIMG;  // uint4 cells
    hipLaunchKernelGGL(fill_zero_u4, dim3((nfill + 255) / 256), dim3(256), 0, stream,
                       px, nfill);
    hipLaunchKernelGGL(pack_weights, dim3((OC * NTAP + 255) / 256), dim3(256), 0, stream,
                       wts, wpk, popcw);
    hipLaunchKernelGGL(mk_base, dim3((9 * OC + 255) / 256), dim3(256), 0, stream,
                       popcw, baset);
    hipLaunchKernelGGL(pack_x, dim3((NIMG * 4 * (HWSZ / 4) + 255) / 256), dim3(256), 0, stream,
                       x, (uint32_t*)px);
    hipLaunchKernelGGL(bconv, dim3(NIMG * 49, 4), dim3(256), 0, stream,
                       px, wpk, baset, out);
}

// Round 5
// 179.688 us; speedup vs baseline: 1.0744x; 1.0744x over previous
//
#include <hip/hip_runtime.h>
#include <cstdint>
#include <cstddef>

// Problem constants
#define NIMG 32
#define C    128
#define OC   128
#define HW   112
#define HWSZ (HW * HW)      // 12544
#define PHW  114            // padded spatial dim
#define PIMG (PHW * PHW)    // 12996 padded cells per image
#define NTAP 9
#define OSUB 8              // output channels per thread
#define NSLAB (OC / OSUB)   // 16 o-slabs (blockIdx.y)
#define PX   4              // pixels per thread (consecutive w)

// ---------------------------------------------------------------------------
// Zero-fill the padded packed-x buffer (borders must read as 0 bits).
__global__ void fill_zero_u4(uint4* __restrict__ p, int n) {
    int i = blockIdx.x * blockDim.x + threadIdx.x;
    if (i < n) p[i] = make_uint4(0u, 0u, 0u, 0u);
}

// ---------------------------------------------------------------------------
// Pack weights via ballot: block = one output channel o (128 blocks x 128 thr).
// Thread c reads its 9 contiguous taps; per tap, __ballot across the wave
// packs 64 channel sign bits in one op. Lane t of each wave writes tap t's
// 64-bit half. Fully parallel, no serial 128-iteration loop.
__global__ void pack_weights(const float* __restrict__ w, uint4* __restrict__ wpk) {
    int o = blockIdx.x;
    int c = threadIdx.x;                 // 0..127
    int wave = c >> 6, lane = c & 63;
    const float* wp = w + ((size_t)o * C + c) * NTAP;
    uint32_t sb[NTAP];
    #pragma unroll
    for (int t = 0; t < NTAP; ++t) sb[t] = __float_as_uint(wp[t]) >> 31;
    #pragma unroll
    for (int t = 0; t < NTAP; ++t) {
        unsigned long long m = __ballot(sb[t]);
        if (lane == t) {
            uint2* dst = reinterpret_cast<uint2*>(&wpk[o * NTAP + t]);
            dst[wave] = make_uint2((uint32_t)m, (uint32_t)(m >> 32));
        }
    }
}

// ---------------------------------------------------------------------------
// Border-base table: base[pat][o] = 9*C - sum over invalid taps of
// (C - 2*popc(W_tap)), so out = base - 2*popc_total. Popcounts taken from wpk.
__global__ void mk_base(const uint4* __restrict__ wpk, int* __restrict__ baset) {
    int idx = blockIdx.x * blockDim.x + threadIdx.x;   // pat*128 + o
    if (idx >= 9 * OC) return;
    int pat = idx >> 7, o = idx & 127;
    int pt = pat / 3, pw = pat % 3;
    int inv = 0;
    if (pt == 1) inv |= 0b000000111;
    if (pt == 2) inv |= 0b111000000;
    if (pw == 1) inv |= 0b001001001;
    if (pw == 2) inv |= 0b100100100;
    int s = NTAP * C;
    for (int t = 0; t < NTAP; ++t)
        if ((inv >> t) & 1) {
            uint4 m = wpk[o * NTAP + t];
            int pc = __popc(m.x) + __popc(m.y) + __popc(m.z) + __popc(m.w);
            s -= C - 2 * pc;
        }
    baset[idx] = s;
}

// ---------------------------------------------------------------------------
// Pack activations: x (N,C,112,112) fp32 -> padded bit buffer.
// One thread = (n, word-of-32-channels, 4 consecutive w positions).
__global__ void pack_x(const float* __restrict__ x, uint32_t* __restrict__ pxw) {
    int t = blockIdx.x * blockDim.x + threadIdx.x;
    const int per_img = HWSZ / 4;                      // 3136
    if (t >= NIMG * 4 * per_img) return;
    int p = t % per_img;                               // lane-fastest -> coalesced
    int g = t / per_img;
    int word = g & 3, n = g >> 2;
    int hw0 = p * 4;
    int h = hw0 / HW, w0 = hw0 % HW;                   // no row crossing

    uint32_t m[4] = {0u, 0u, 0u, 0u};
    const float* xp = x + ((size_t)n * C + word * 32) * HWSZ + hw0;
    #pragma unroll
    for (int cc = 0; cc < 32; ++cc) {
        float4 v = *reinterpret_cast<const float4*>(xp + (size_t)cc * HWSZ);
        m[0] |= (__float_as_uint(v.x) >> 31) << cc;
        m[1] |= (__float_as_uint(v.y) >> 31) << cc;
        m[2] |= (__float_as_uint(v.z) >> 31) << cc;
        m[3] |= (__float_as_uint(v.w) >> 31) << cc;
    }
    uint32_t* dst = pxw + (((size_t)n * PIMG + (size_t)(h + 1) * PHW + (w0 + 1)) << 2) + word;
    dst[0]  = m[0];
    dst[4]  = m[1];
    dst[8]  = m[2];
    dst[12] = m[3];
}

// ---------------------------------------------------------------------------
__device__ __forceinline__ void bcnt_acc(uint32_t& acc, uint32_t v) {
    // acc = popc(v) + acc, single instruction
    asm("v_bcnt_u32_b32 %0, %1, %0" : "+v"(acc) : "v"(v));
}

// Binary conv, register-blocked: thread = (4 consecutive pixels) x (8 o).
// Each LDS weight read (ds_read_b128 broadcast) now feeds 32 VALU ops
// (4 pixels x 4 words x xor+bcnt) instead of 8 -> LDS pipe time ~31 us/CU,
// hidden under the ~50 us VALU floor. X-taps (3 rows x 6 uint4) come from
// global memory (L1/L2-hot padded bit buffer) on the vmem pipe.
__global__ __launch_bounds__(256, 4) void bconv(const uint4* __restrict__ px,
                                                const uint4* __restrict__ wpk,
                                                const int* __restrict__ baset,
                                                float* __restrict__ out) {
    __shared__ uint4 swt[NTAP][OSUB];   // [tap][o], 1.15 KB
    __shared__ int sbase[9 * OSUB];     // base[pat][o-slab]

    int o0 = blockIdx.y * OSUB;
    if (threadIdx.x < NTAP * OSUB) {
        int t = threadIdx.x / OSUB, o = threadIdx.x % OSUB;
        swt[t][o] = wpk[(size_t)(o0 + o) * NTAP + t];
    }
    if (threadIdx.x >= 128 && threadIdx.x < 128 + 9 * OSUB) {
        int i = threadIdx.x - 128;
        sbase[i] = baset[(i / OSUB) * OC + o0 + (i % OSUB)];
    }
    __syncthreads();

    int t = blockIdx.x * 256 + threadIdx.x;     // 0 .. 100351
    int n = t / (HWSZ / PX);                    // / 3136
    int p = t % (HWSZ / PX);
    int h = p / (HW / PX);                      // / 28
    int w0 = (p % (HW / PX)) * PX;
    int hw0 = h * HW + w0;

    uint32_t acc[PX][OSUB];
    #pragma unroll
    for (int q = 0; q < PX; ++q)
        #pragma unroll
        for (int o = 0; o < OSUB; ++o) acc[q][o] = 0u;

    const uint4* ib = px + (size_t)n * PIMG;
    #pragma unroll
    for (int kh = 0; kh < 3; ++kh) {
        const uint4* rb = ib + (size_t)(h + kh) * PHW + w0;  // padded: col w0 = tap kw=0
        uint4 xr[PX + 2];
        #pragma unroll
        for (int j = 0; j < PX + 2; ++j) xr[j] = rb[j];
        #pragma unroll
        for (int o = 0; o < OSUB; ++o) {
            #pragma unroll
            for (int kw = 0; kw < 3; ++kw) {
                uint4 wv = swt[kh * 3 + kw][o];   // uniform ds_read_b128 broadcast
                #pragma unroll
                for (int q = 0; q < PX; ++q) {
                    bcnt_acc(acc[q][o], xr[q + kw].x ^ wv.x);
                    bcnt_acc(acc[q][o], xr[q + kw].y ^ wv.y);
                    bcnt_acc(acc[q][o], xr[q + kw].z ^ wv.z);
                    bcnt_acc(acc[q][o], xr[q + kw].w ^ wv.w);
                }
            }
        }
    }

    int pt = (h == 0) ? 1 : ((h == HW - 1) ? 2 : 0);
    float* ob = out + ((size_t)n * OC + o0) * HWSZ + hw0;
    #pragma unroll
    for (int o = 0; o < OSUB; ++o) {
        float4 v;
        #pragma unroll
        for (int q = 0; q < PX; ++q) {
            int pw = (q == 0) ? ((w0 == 0) ? 1 : 0)
                   : ((q == PX - 1) ? ((w0 + PX - 1 == HW - 1) ? 2 : 0) : 0);
            int b = sbase[(pt * 3 + pw) * OSUB + o];
            (&v.x)[q] = (float)(b - 2 * (int)acc[q][o]);
        }
        *reinterpret_cast<float4*>(ob + (size_t)o * HWSZ) = v;   // 16B coalesced
    }
}

// ---------------------------------------------------------------------------
extern "C" void kernel_launch(void* const* d_in, const int* in_sizes, int n_in,
                              void* d_out, int out_size, void* d_ws, size_t ws_size,
                              hipStream_t stream) {
    const float* x   = (const float*)d_in[0];
    const float* wts = (const float*)d_in[1];
    float* out = (float*)d_out;

    uint8_t* ws = (uint8_t*)d_ws;
    size_t px_bytes  = (size_t)NIMG * PIMG * sizeof(uint4);   // 6,653,952
    size_t wpk_bytes = (size_t)OC * NTAP * sizeof(uint4);     // 18,432
    uint4* px    = (uint4*)ws;
    uint4* wpk   = (uint4*)(ws + px_bytes);
    int*   baset = (int*)(ws + px_bytes + wpk_bytes);

    int nfill = NIMG * PIMG;  // uint4 cells
    hipLaunchKernelGGL(fill_zero_u4, dim3((nfill + 255) / 256), dim3(256), 0, stream,
                       px, nfill);
    hipLaunchKernelGGL(pack_weights, dim3(OC), dim3(C), 0, stream, wts, wpk);
    hipLaunchKernelGGL(mk_base, dim3((9 * OC + 255) / 256), dim3(256), 0, stream,
                       wpk, baset);
    hipLaunchKernelGGL(pack_x, dim3((NIMG * 4 * (HWSZ / 4) + 255) / 256), dim3(256), 0, stream,
                       x, (uint32_t*)px);
    hipLaunchKernelGGL(bconv, dim3(NIMG * (HWSZ / PX) / 256, NSLAB), dim3(256), 0, stream,
                       px, wpk, baset, out);
}

// Round 6
// 149.487 us; speedup vs baseline: 1.2915x; 1.2020x over previous
//
#include <hip/hip_runtime.h>
#include <cstdint>
#include <cstddef>

// Problem constants
#define NIMG 32
#define C    128
#define OC   128
#define HW   112
#define HWSZ (HW * HW)       // 12544
#define NTAP 9
// channel-last padded activation buffer: xq[n][114][114][128] int8
#define PHW  114
#define XROW (PHW * C)       // 14592 B per padded row
#define XIMG (PHW * XROW)    // 1,663,488 B per image
#define XQ_BYTES ((size_t)NIMG * XIMG)          // 53,231,616
#define AWQ_BYTES ((size_t)8 * 9 * 2 * 64 * 16) // 147,456
#define WS_NEED (XQ_BYTES + AWQ_BYTES)

typedef int v4i __attribute__((ext_vector_type(4)));

// ===========================================================================
// MFMA PATH
// ===========================================================================

// sign byte: +1 (0x01) if x>=0 else -1 (0xFF)
__device__ __forceinline__ uint32_t sign_byte(uint32_t bits) {
    return ((bits >> 31) * 0xFEu) ^ 1u;
}

// Zero the border cells of xq (rows 0,113 full; cols 0,113 for rows 1..112).
__global__ void fill_border(uint8_t* __restrict__ xq) {
    int tid = blockIdx.x * blockDim.x + threadIdx.x;   // 32*3616 total
    int n = tid / 3616, u = tid % 3616;
    size_t off;
    if (u < 912)        off = (size_t)u * 16;                          // top row
    else if (u < 1824)  off = (size_t)113 * XROW + (size_t)(u - 912) * 16; // bottom
    else {
        int j = u - 1824;                 // 0..1791
        int r = (j >> 4) + 1;             // rows 1..112
        int side = (j >> 3) & 1;          // 0=left col, 1=right col
        int cu = j & 7;
        off = (size_t)r * XROW + (size_t)side * (113 * C) + (size_t)cu * 16;
    }
    *(uint4*)(xq + (size_t)n * XIMG + off) = make_uint4(0u, 0u, 0u, 0u);
}

// Pack x (N,C,112,112) fp32 -> xq channel-last int8 via LDS transpose.
// Block = one (n, h) row: read coalesced along w, write 14336B contiguous.
__global__ __launch_bounds__(256) void pack_x_cl(const float* __restrict__ x,
                                                 uint8_t* __restrict__ xq) {
    __shared__ __align__(16) uint8_t slds[112 * 144];   // [px][c], pad 144
    int n = blockIdx.x / HW, h = blockIdx.x % HW;

    #pragma unroll
    for (int rep = 0; rep < 2; ++rep) {
        int task = threadIdx.x + rep * 256;
        if (task < 448) {
            int px = task % HW;           // consecutive lanes -> consecutive px
            int word = task / HW;         // 32-channel group
            const float* xp = x + ((size_t)(n * C + word * 32)) * HWSZ + h * HW + px;
            uint8_t* sp = &slds[px * 144 + word * 32];
            uint32_t dw[8];
            #pragma unroll
            for (int i = 0; i < 8; ++i) {
                uint32_t acc = 0;
                #pragma unroll
                for (int b = 0; b < 4; ++b) {
                    uint32_t bits = __float_as_uint(xp[(size_t)(i * 4 + b) * HWSZ]);
                    acc |= sign_byte(bits) << (8 * b);
                }
                dw[i] = acc;
            }
            *(uint4*)sp        = make_uint4(dw[0], dw[1], dw[2], dw[3]);
            *(uint4*)(sp + 16) = make_uint4(dw[4], dw[5], dw[6], dw[7]);
        }
    }
    __syncthreads();
    uint8_t* dst = xq + (size_t)n * XIMG + (size_t)(h + 1) * XROW + C;  // col 1
    #pragma unroll
    for (int rep = 0; rep < 4; ++rep) {
        int u = threadIdx.x + rep * 256;
        if (u < 896) {                          // 896*16 = 14336 B = cols 1..112
            int px = u >> 3, c16 = (u & 7) * 16;
            *(uint4*)(dst + (size_t)u * 16) = *(const uint4*)&slds[px * 144 + c16];
        }
    }
}

// Build A-fragments for mfma_i32_16x16x64_i8:
// awq[f][lane][16B], f = ((o16*9 + tap)*2 + ks); lane l: row m=l&15, k=(l>>4)*16+j.
// A[m][k] = sign(w[o16*16+m][ks*64+(l>>4)*16+j][tap])
__global__ void pack_w_frag(const float* __restrict__ w, uint32_t* __restrict__ awq) {
    int tid = blockIdx.x * blockDim.x + threadIdx.x;   // 36864 dwords
    int d = tid & 3, l = (tid >> 2) & 63, f = tid >> 8;
    int ks = f & 1, tf = f >> 1;
    int tap = tf % 9, o16 = tf / 9;
    int o = o16 * 16 + (l & 15);
    int cb = ks * 64 + ((l >> 4) & 3) * 16 + d * 4;
    uint32_t acc = 0;
    #pragma unroll
    for (int jj = 0; jj < 4; ++jj) {
        uint32_t bits = __float_as_uint(w[(size_t)(o * C + cb + jj) * NTAP + tap]);
        acc |= sign_byte(bits) << (8 * jj);
    }
    awq[tid] = acc;
}

// Binary conv as int8 implicit GEMM.
// Block = (n, h): stage padded rows h..h+2 (43776 B, 16B-granule XOR swizzle)
// into LDS; 4 waves x 32 output channels; 7 N-tiles of 16 pixels; per tile
// 18 ds_read_b128 (B frags) + 36 v_mfma_i32_16x16x64_i8. 0-padding makes
// borders exact -- no correction.
__global__ __launch_bounds__(256, 2) void bconv_mfma(const uint8_t* __restrict__ xq,
                                                     const uint8_t* __restrict__ awq,
                                                     float* __restrict__ out) {
    __shared__ __align__(16) uint8_t sxq[3 * XROW];    // 43776 B
    int n = blockIdx.x / HW, h = blockIdx.x % HW;

    const uint8_t* src = xq + (size_t)n * XIMG + (size_t)h * XROW;
    #pragma unroll
    for (int rep = 0; rep < 11; ++rep) {
        int u = threadIdx.x + rep * 256;
        if (u < 2736) {
            int pix = (u >> 3) % PHW;                  // col within padded row
            uint4 v = *(const uint4*)(src + (size_t)u * 16);
            int a = (u * 16) ^ ((pix & 7) << 4);       // swizzle within 128B block
            *(uint4*)&sxq[a] = v;
        }
    }

    int wv = threadIdx.x >> 6, l = threadIdx.x & 63;
    int l15 = l & 15, lk = (l >> 4) * 16;

    // resident A fragments: 2 o-tiles x 9 taps x 2 k-slices (144 VGPR)
    v4i A[2][9][2];
    #pragma unroll
    for (int ot = 0; ot < 2; ++ot)
        #pragma unroll
        for (int tap = 0; tap < 9; ++tap)
            #pragma unroll
            for (int ks = 0; ks < 2; ++ks) {
                int f = ((wv * 2 + ot) * 9 + tap) * 2 + ks;
                A[ot][tap][ks] = *(const v4i*)(awq + (size_t)f * 1024 + (size_t)l * 16);
            }
    __syncthreads();

    float* outb = out + ((size_t)n * OC + wv * 32) * HWSZ + h * HW;

    for (int nt = 0; nt < 7; ++nt) {
        int w0 = nt * 16;
        int ad[3][2];
        #pragma unroll
        for (int kw = 0; kw < 3; ++kw) {
            int pix = w0 + l15 + kw;                   // padded col, always in-bounds
            int x4 = (pix & 7) << 4;
            int base = pix * C;
            ad[kw][0] = base + (lk ^ x4);
            ad[kw][1] = base + ((lk + 64) ^ x4);
        }
        v4i acc0 = {0, 0, 0, 0}, acc1 = {0, 0, 0, 0};
        #pragma unroll
        for (int kh = 0; kh < 3; ++kh)
            #pragma unroll
            for (int kw = 0; kw < 3; ++kw)
                #pragma unroll
                for (int ks = 0; ks < 2; ++ks) {
                    v4i b = *(const v4i*)&sxq[kh * XROW + ad[kw][ks]];
                    acc0 = __builtin_amdgcn_mfma_i32_16x16x64_i8(
                               A[0][kh * 3 + kw][ks], b, acc0, 0, 0, 0);
                    acc1 = __builtin_amdgcn_mfma_i32_16x16x64_i8(
                               A[1][kh * 3 + kw][ks], b, acc1, 0, 0, 0);
                }
        #pragma unroll
        for (int r = 0; r < 4; ++r) {
            int oof = ((l >> 4) << 2) + r;             // D: col=l&15, row=(l>>4)*4+r
            outb[(size_t)oof * HWSZ + w0 + l15]        = (float)acc0[r];
            outb[(size_t)(oof + 16) * HWSZ + w0 + l15] = (float)acc1[r];
        }
    }
}

// ===========================================================================
// FALLBACK PATH (R5 popcount; used only if ws_size < WS_NEED)
// ===========================================================================
#define PIMG (PHW * PHW)
#define OSUB 8
#define NSLAB (OC / OSUB)
#define PX 4

__global__ void fill_zero_u4(uint4* __restrict__ p, int n) {
    int i = blockIdx.x * blockDim.x + threadIdx.x;
    if (i < n) p[i] = make_uint4(0u, 0u, 0u, 0u);
}
__global__ void pack_weights_fb(const float* __restrict__ w, uint4* __restrict__ wpk) {
    int o = blockIdx.x, c = threadIdx.x;
    int wave = c >> 6, lane = c & 63;
    const float* wp = w + ((size_t)o * C + c) * NTAP;
    uint32_t sb[NTAP];
    #pragma unroll
    for (int t = 0; t < NTAP; ++t) sb[t] = __float_as_uint(wp[t]) >> 31;
    #pragma unroll
    for (int t = 0; t < NTAP; ++t) {
        unsigned long long m = __ballot(sb[t]);
        if (lane == t) {
            uint2* dst = reinterpret_cast<uint2*>(&wpk[o * NTAP + t]);
            dst[wave] = make_uint2((uint32_t)m, (uint32_t)(m >> 32));
        }
    }
}
__global__ void mk_base_fb(const uint4* __restrict__ wpk, int* __restrict__ baset) {
    int idx = blockIdx.x * blockDim.x + threadIdx.x;
    if (idx >= 9 * OC) return;
    int pat = idx >> 7, o = idx & 127;
    int pt = pat / 3, pw = pat % 3;
    int inv = 0;
    if (pt == 1) inv |= 0b000000111;
    if (pt == 2) inv |= 0b111000000;
    if (pw == 1) inv |= 0b001001001;
    if (pw == 2) inv |= 0b100100100;
    int s = NTAP * C;
    for (int t = 0; t < NTAP; ++t)
        if ((inv >> t) & 1) {
            uint4 m = wpk[o * NTAP + t];
            s -= C - 2 * (__popc(m.x) + __popc(m.y) + __popc(m.z) + __popc(m.w));
        }
    baset[idx] = s;
}
__global__ void pack_x_fb(const float* __restrict__ x, uint32_t* __restrict__ pxw) {
    int t = blockIdx.x * blockDim.x + threadIdx.x;
    const int per_img = HWSZ / 4;
    if (t >= NIMG * 4 * per_img) return;
    int p = t % per_img, g = t / per_img;
    int word = g & 3, n = g >> 2;
    int hw0 = p * 4, h = hw0 / HW, w0 = hw0 % HW;
    uint32_t m[4] = {0u, 0u, 0u, 0u};
    const float* xp = x + ((size_t)n * C + word * 32) * HWSZ + hw0;
    #pragma unroll
    for (int cc = 0; cc < 32; ++cc) {
        float4 v = *reinterpret_cast<const float4*>(xp + (size_t)cc * HWSZ);
        m[0] |= (__float_as_uint(v.x) >> 31) << cc;
        m[1] |= (__float_as_uint(v.y) >> 31) << cc;
        m[2] |= (__float_as_uint(v.z) >> 31) << cc;
        m[3] |= (__float_as_uint(v.w) >> 31) << cc;
    }
    uint32_t* dst = pxw + (((size_t)n * PIMG + (size_t)(h + 1) * PHW + (w0 + 1)) << 2) + word;
    dst[0] = m[0]; dst[4] = m[1]; dst[8] = m[2]; dst[12] = m[3];
}
__device__ __forceinline__ void bcnt_acc(uint32_t& acc, uint32_t v) {
    asm("v_bcnt_u32_b32 %0, %1, %0" : "+v"(acc) : "v"(v));
}
__global__ __launch_bounds__(256, 4) void bconv_fb(const uint4* __restrict__ px,
                                                   const uint4* __restrict__ wpk,
                                                   const int* __restrict__ baset,
                                                   float* __restrict__ out) {
    __shared__ uint4 swt[NTAP][OSUB];
    __shared__ int sbase[9 * OSUB];
    int o0 = blockIdx.y * OSUB;
    if (threadIdx.x < NTAP * OSUB) {
        int t = threadIdx.x / OSUB, o = threadIdx.x % OSUB;
        swt[t][o] = wpk[(size_t)(o0 + o) * NTAP + t];
    }
    if (threadIdx.x >= 128 && threadIdx.x < 128 + 9 * OSUB) {
        int i = threadIdx.x - 128;
        sbase[i] = baset[(i / OSUB) * OC + o0 + (i % OSUB)];
    }
    __syncthreads();
    int t = blockIdx.x * 256 + threadIdx.x;
    int n = t / (HWSZ / PX), p = t % (HWSZ / PX);
    int h = p / (HW / PX), w0 = (p % (HW / PX)) * PX;
    int hw0 = h * HW + w0;
    uint32_t acc[PX][OSUB];
    #pragma unroll
    for (int q = 0; q < PX; ++q)
        #pragma unroll
        for (int o = 0; o < OSUB; ++o) acc[q][o] = 0u;
    const uint4* ib = px + (size_t)n * PIMG;
    #pragma unroll
    for (int kh = 0; kh < 3; ++kh) {
        const uint4* rb = ib + (size_t)(h + kh) * PHW + w0;
        uint4 xr[PX + 2];
        #pragma unroll
        for (int j = 0; j < PX + 2; ++j) xr[j] = rb[j];
        #pragma unroll
        for (int o = 0; o < OSUB; ++o)
            #pragma unroll
            for (int kw = 0; kw < 3; ++kw) {
                uint4 wv = swt[kh * 3 + kw][o];
                #pragma unroll
                for (int q = 0; q < PX; ++q) {
                    bcnt_acc(acc[q][o], xr[q + kw].x ^ wv.x);
                    bcnt_acc(acc[q][o], xr[q + kw].y ^ wv.y);
                    bcnt_acc(acc[q][o], xr[q + kw].z ^ wv.z);
                    bcnt_acc(acc[q][o], xr[q + kw].w ^ wv.w);
                }
            }
    }
    int pt = (h == 0) ? 1 : ((h == HW - 1) ? 2 : 0);
    float* ob = out + ((size_t)n * OC + o0) * HWSZ + hw0;
    #pragma unroll
    for (int o = 0; o < OSUB; ++o) {
        float4 v;
        #pragma unroll
        for (int q = 0; q < PX; ++q) {
            int pw = (q == 0) ? ((w0 == 0) ? 1 : 0)
                   : ((q == PX - 1) ? ((w0 + PX - 1 == HW - 1) ? 2 : 0) : 0);
            int b = sbase[(pt * 3 + pw) * OSUB + o];
            (&v.x)[q] = (float)(b - 2 * (int)acc[q][o]);
        }
        *reinterpret_cast<float4*>(ob + (size_t)o * HWSZ) = v;
    }
}

// ===========================================================================
extern "C" void kernel_launch(void* const* d_in, const int* in_sizes, int n_in,
                              void* d_out, int out_size, void* d_ws, size_t ws_size,
                              hipStream_t stream) {
    const float* x   = (const float*)d_in[0];
    const float* wts = (const float*)d_in[1];
    float* out = (float*)d_out;
    uint8_t* ws = (uint8_t*)d_ws;

    if (ws_size >= WS_NEED) {
        uint8_t*  xq  = ws;
        uint32_t* awq = (uint32_t*)(ws + XQ_BYTES);

        hipLaunchKernelGGL(fill_border, dim3(NIMG * 3616 / 256), dim3(256), 0, stream, xq);
        hipLaunchKernelGGL(pack_w_frag, dim3(144), dim3(256), 0, stream, wts, awq);
        hipLaunchKernelGGL(pack_x_cl, dim3(NIMG * HW), dim3(256), 0, stream, x, xq);
        hipLaunchKernelGGL(bconv_mfma, dim3(NIMG * HW), dim3(256), 0, stream,
                           xq, (const uint8_t*)awq, out);
    } else {
        size_t px_bytes  = (size_t)NIMG * PIMG * sizeof(uint4);
        size_t wpk_bytes = (size_t)OC * NTAP * sizeof(uint4);
        uint4* px    = (uint4*)ws;
        uint4* wpk   = (uint4*)(ws + px_bytes);
        int*   baset = (int*)(ws + px_bytes + wpk_bytes);
        int nfill = NIMG * PIMG;
        hipLaunchKernelGGL(fill_zero_u4, dim3((nfill + 255) / 256), dim3(256), 0, stream,
                           px, nfill);
        hipLaunchKernelGGL(pack_weights_fb, dim3(OC), dim3(C), 0, stream, wts, wpk);
        hipLaunchKernelGGL(mk_base_fb, dim3((9 * OC + 255) / 256), dim3(256), 0, stream,
                           wpk, baset);
        hipLaunchKernelGGL(pack_x_fb, dim3((NIMG * 4 * (HWSZ / 4) + 255) / 256), dim3(256),
                           0, stream, x, (uint32_t*)px);
        hipLaunchKernelGGL(bconv_fb, dim3(NIMG * (HWSZ / PX) / 256, NSLAB), dim3(256),
                           0, stream, px, wpk, baset, out);
    }
}

// Round 7
// 140.145 us; speedup vs baseline: 1.3776x; 1.0667x over previous
//
#include <hip/hip_runtime.h>
#include <cstdint>
#include <cstddef>

// Problem constants
#define NIMG 32
#define C    128
#define OC   128
#define HW   112
#define HWSZ (HW * HW)       // 12544
#define NTAP 9
// channel-last padded activation buffer: xq[n][114][114][128] int8
#define PHW  114
#define XROW (PHW * C)       // 14592 B per padded row
#define XIMG (PHW * XROW)    // 1,663,488 B per image
#define XQ_BYTES ((size_t)NIMG * XIMG)          // 53,231,616
#define AWQ_BYTES ((size_t)8 * 9 * 2 * 64 * 16) // 147,456

typedef int v4i __attribute__((ext_vector_type(4)));

// sign byte: +1 (0x01) if x>=0 else -1 (0xFF)
__device__ __forceinline__ uint32_t sign_byte(uint32_t bits) {
    return ((bits >> 31) * 0xFEu) ^ 1u;
}

// ---------------------------------------------------------------------------
// Zero the border cells of xq (rows 0,113 full; cols 0,113 for rows 1..112).
__global__ void fill_border(uint8_t* __restrict__ xq) {
    int tid = blockIdx.x * blockDim.x + threadIdx.x;   // 32*3616 total
    int n = tid / 3616, u = tid % 3616;
    size_t off;
    if (u < 912)        off = (size_t)u * 16;                              // top row
    else if (u < 1824)  off = (size_t)113 * XROW + (size_t)(u - 912) * 16; // bottom
    else {
        int j = u - 1824;                 // 0..1791
        int r = (j >> 4) + 1;             // rows 1..112
        int side = (j >> 3) & 1;          // 0=left col, 1=right col
        int cu = j & 7;
        off = (size_t)r * XROW + (size_t)side * (113 * C) + (size_t)cu * 16;
    }
    *(uint4*)(xq + (size_t)n * XIMG + off) = make_uint4(0u, 0u, 0u, 0u);
}

// ---------------------------------------------------------------------------
// Pack x (N,C,112,112) fp32 -> xq channel-last int8 via LDS transpose.
// Block = (n, pair of rows). Load phase: 224 threads x 32 float4 loads
// (16 B/lane, 448B contiguous per wave-group). Write: 28672B contiguous.
__global__ __launch_bounds__(256) void pack_x_cl(const float* __restrict__ x,
                                                 uint8_t* __restrict__ xq) {
    __shared__ __align__(16) uint8_t slds[2 * 112 * 144];   // [row][px][c], pad 144
    int n = blockIdx.x / 56, hp = blockIdx.x % 56;
    int h0 = hp * 2;

    int task = threadIdx.x;
    if (task < 224) {
        int r = task / 112, rem = task % 112;
        int word = rem / 28, pxg = rem % 28;      // consecutive lanes -> consecutive px4
        const float* xp = x + ((size_t)(n * C + word * 32)) * HWSZ
                            + (size_t)(h0 + r) * HW + pxg * 4;
        uint32_t dw[4][8];
        #pragma unroll
        for (int i = 0; i < 8; ++i) {
            uint32_t a0 = 0, a1 = 0, a2 = 0, a3 = 0;
            #pragma unroll
            for (int b = 0; b < 4; ++b) {
                float4 v = *reinterpret_cast<const float4*>(xp + (size_t)(i * 4 + b) * HWSZ);
                a0 |= sign_byte(__float_as_uint(v.x)) << (8 * b);
                a1 |= sign_byte(__float_as_uint(v.y)) << (8 * b);
                a2 |= sign_byte(__float_as_uint(v.z)) << (8 * b);
                a3 |= sign_byte(__float_as_uint(v.w)) << (8 * b);
            }
            dw[0][i] = a0; dw[1][i] = a1; dw[2][i] = a2; dw[3][i] = a3;
        }
        #pragma unroll
        for (int j = 0; j < 4; ++j) {
            uint8_t* sp = &slds[(size_t)((r * 112) + pxg * 4 + j) * 144 + word * 32];
            *(uint4*)sp        = make_uint4(dw[j][0], dw[j][1], dw[j][2], dw[j][3]);
            *(uint4*)(sp + 16) = make_uint4(dw[j][4], dw[j][5], dw[j][6], dw[j][7]);
        }
    }
    __syncthreads();

    uint8_t* dst = xq + (size_t)n * XIMG + (size_t)(h0 + 1) * XROW + C;  // col 1
    #pragma unroll
    for (int rep = 0; rep < 7; ++rep) {
        int u = threadIdx.x + rep * 256;          // < 1792
        int row = u / 896, i = u % 896;           // 896*16B = cols 1..112 of one row
        *(uint4*)(dst + (size_t)row * XROW + (size_t)i * 16) =
            *(const uint4*)&slds[(size_t)(row * 112 + (i >> 3)) * 144 + (i & 7) * 16];
    }
}

// ---------------------------------------------------------------------------
// Build A-fragments for mfma_i32_16x16x64_i8:
// awq[f][lane][16B], f = ((o16*9 + tap)*2 + ks); lane l: row m=l&15, k=(l>>4)*16+j.
__global__ void pack_w_frag(const float* __restrict__ w, uint32_t* __restrict__ awq) {
    int tid = blockIdx.x * blockDim.x + threadIdx.x;   // 36864 dwords
    int d = tid & 3, l = (tid >> 2) & 63, f = tid >> 8;
    int ks = f & 1, tf = f >> 1;
    int tap = tf % 9, o16 = tf / 9;
    int o = o16 * 16 + (l & 15);
    int cb = ks * 64 + ((l >> 4) & 3) * 16 + d * 4;
    uint32_t acc = 0;
    #pragma unroll
    for (int jj = 0; jj < 4; ++jj) {
        uint32_t bits = __float_as_uint(w[(size_t)(o * C + cb + jj) * NTAP + tap]);
        acc |= sign_byte(bits) << (8 * jj);
    }
    awq[tid] = acc;
}

// ---------------------------------------------------------------------------
// Binary conv as int8 implicit GEMM.
// Block = (n, h), XCD-swizzled so each XCD gets 4 contiguous images (448 rows):
// adjacent-h blocks share 2 of 3 staged xq rows -> L2 hits instead of HBM.
// Stage 3 padded rows (43776 B, 16B-granule XOR swizzle) into LDS; 4 waves x
// 32 output channels; 7 N-tiles of 16 px; per tile 18 ds_read_b128 + 36 MFMA.
__global__ __launch_bounds__(256, 2) void bconv_mfma(const uint8_t* __restrict__ xq,
                                                     const uint8_t* __restrict__ awq,
                                                     float* __restrict__ out) {
    __shared__ __align__(16) uint8_t sxq[3 * XROW];    // 43776 B
    int bid = blockIdx.x;                              // 3584 = 8 * 448, bijective
    int swz = (bid & 7) * 448 + (bid >> 3);
    int n = swz / HW, h = swz % HW;

    const uint8_t* src = xq + (size_t)n * XIMG + (size_t)h * XROW;
    #pragma unroll
    for (int rep = 0; rep < 11; ++rep) {
        int u = threadIdx.x + rep * 256;
        if (u < 2736) {
            int pix = (u >> 3) % PHW;                  // col within padded row
            uint4 v = *(const uint4*)(src + (size_t)u * 16);
            int a = (u * 16) ^ ((pix & 7) << 4);       // swizzle within 128B block
            *(uint4*)&sxq[a] = v;
        }
    }

    int wv = threadIdx.x >> 6, l = threadIdx.x & 63;
    int l15 = l & 15, lk = (l >> 4) * 16;

    // resident A fragments: 2 o-tiles x 9 taps x 2 k-slices (144 VGPR)
    v4i A[2][9][2];
    #pragma unroll
    for (int ot = 0; ot < 2; ++ot)
        #pragma unroll
        for (int tap = 0; tap < 9; ++tap)
            #pragma unroll
            for (int ks = 0; ks < 2; ++ks) {
                int f = ((wv * 2 + ot) * 9 + tap) * 2 + ks;
                A[ot][tap][ks] = *(const v4i*)(awq + (size_t)f * 1024 + (size_t)l * 16);
            }
    __syncthreads();

    float* outb = out + ((size_t)n * OC + wv * 32) * HWSZ + h * HW;

    for (int nt = 0; nt < 7; ++nt) {
        int w0 = nt * 16;
        int ad[3][2];
        #pragma unroll
        for (int kw = 0; kw < 3; ++kw) {
            int pix = w0 + l15 + kw;                   // padded col, always in-bounds
            int x4 = (pix & 7) << 4;
            int base = pix * C;
            ad[kw][0] = base + (lk ^ x4);
            ad[kw][1] = base + ((lk + 64) ^ x4);
        }
        v4i acc0 = {0, 0, 0, 0}, acc1 = {0, 0, 0, 0};
        #pragma unroll
        for (int kh = 0; kh < 3; ++kh)
            #pragma unroll
            for (int kw = 0; kw < 3; ++kw)
                #pragma unroll
                for (int ks = 0; ks < 2; ++ks) {
                    v4i b = *(const v4i*)&sxq[kh * XROW + ad[kw][ks]];
                    acc0 = __builtin_amdgcn_mfma_i32_16x16x64_i8(
                               A[0][kh * 3 + kw][ks], b, acc0, 0, 0, 0);
                    acc1 = __builtin_amdgcn_mfma_i32_16x16x64_i8(
                               A[1][kh * 3 + kw][ks], b, acc1, 0, 0, 0);
                }
        #pragma unroll
        for (int r = 0; r < 4; ++r) {
            int oof = ((l >> 4) << 2) + r;             // D: col=l&15, row=(l>>4)*4+r
            outb[(size_t)oof * HWSZ + w0 + l15]        = (float)acc0[r];
            outb[(size_t)(oof + 16) * HWSZ + w0 + l15] = (float)acc1[r];
        }
    }
}

// ===========================================================================
extern "C" void kernel_launch(void* const* d_in, const int* in_sizes, int n_in,
                              void* d_out, int out_size, void* d_ws, size_t ws_size,
                              hipStream_t stream) {
    const float* x   = (const float*)d_in[0];
    const float* wts = (const float*)d_in[1];
    float* out = (float*)d_out;
    uint8_t* ws = (uint8_t*)d_ws;

    uint8_t*  xq  = ws;
    uint32_t* awq = (uint32_t*)(ws + XQ_BYTES);

    hipLaunchKernelGGL(fill_border, dim3(NIMG * 3616 / 256), dim3(256), 0, stream, xq);
    hipLaunchKernelGGL(pack_w_frag, dim3(144), dim3(256), 0, stream, wts, awq);
    hipLaunchKernelGGL(pack_x_cl, dim3(NIMG * 56), dim3(256), 0, stream, x, xq);
    hipLaunchKernelGGL(bconv_mfma, dim3(NIMG * HW), dim3(256), 0, stream,
                       xq, (const uint8_t*)awq, out);
}